// Round 1
// baseline (287.814 us; speedup 1.0000x reference)
//
#include <hip/hip_runtime.h>
#include <hip/hip_bf16.h>

typedef float f32x4 __attribute__((ext_vector_type(4)));
typedef __bf16 bf16x8 __attribute__((ext_vector_type(8)));
typedef unsigned short ushort8 __attribute__((ext_vector_type(8)));

#define DEVINL __device__ __forceinline__

DEVINL void gload_lds16(const void* g, void* l) {
  __builtin_amdgcn_global_load_lds(
      (const __attribute__((address_space(1))) void*)g,
      (__attribute__((address_space(3))) void*)l, 16, 0, 0);
}

DEVINL unsigned short f2bf(float f) {
  unsigned int x = __float_as_uint(f);
  x += 0x7fffu + ((x >> 16) & 1u);
  return (unsigned short)(x >> 16);
}

// Stage a 128-row x 128-byte tile from global (row stride ld_bytes) into LDS.
// XOR-swizzled at 16B granularity: LDS[r][c] holds global[r][c ^ (r&7)].
// Linear LDS dest (wave-uniform base + lane*16) as global_load_lds requires;
// the swizzle is applied on the GLOBAL source address (guide m173 pattern).
DEVINL void stage_tile(const char* gbase, int ld_bytes, char* lds, int tid) {
#pragma unroll
  for (int p = 0; p < 4; ++p) {
    int r = p * 32 + (tid >> 3);
    int cs = (tid & 7) ^ (r & 7);
    gload_lds16(gbase + (size_t)r * ld_bytes + cs * 16, lds + p * 4096 + tid * 16);
  }
}

DEVINL bf16x8 cvt8(f32x4 a, f32x4 b) {
  bf16x8 o;
  o[0] = (__bf16)a[0]; o[1] = (__bf16)a[1]; o[2] = (__bf16)a[2]; o[3] = (__bf16)a[3];
  o[4] = (__bf16)b[0]; o[5] = (__bf16)b[1]; o[6] = (__bf16)b[2]; o[7] = (__bf16)b[3];
  return o;
}

// fragment (8 contiguous K elems per lane) from an f32 tile: row = 32 f32 = 128B
DEVINL bf16x8 frag_from_f32(const char* lds, int r, int kg) {
  int c0 = (kg * 2) ^ (r & 7);
  int c1 = (kg * 2 + 1) ^ (r & 7);
  f32x4 f0 = *(const f32x4*)(lds + r * 128 + c0 * 16);
  f32x4 f1 = *(const f32x4*)(lds + r * 128 + c1 * 16);
  return cvt8(f0, f1);
}

// fragment from a bf16 tile: row = 64 bf16 = 128B; ksub selects 32-wide K slice
DEVINL bf16x8 frag_from_bf16(const char* lds, int r, int kg, int ksub) {
  int c = (ksub * 4 + kg) ^ (r & 7);
  return *(const bf16x8*)(lds + r * 128 + c * 16);
}

// ---------------- GEMM1: qkv = x @ w_qkv^T ----------------
// A = x f32 [65536][256]; B^T = w_qkv f32 [768][256].
// Writes q -> Q bf16 [65536][256], k|v -> KV bf16 [65536][512].
__global__ __launch_bounds__(256) void gemm_qkv(
    const float* __restrict__ X, const float* __restrict__ W,
    __hip_bfloat16* __restrict__ Q, __hip_bfloat16* __restrict__ KV) {
  __shared__ __align__(16) char As[16384];
  __shared__ __align__(16) char Bs[16384];
  int bid = blockIdx.x;
  int swz = (bid & 7) * 384 + (bid >> 3);   // 3072 = 8*384, bijective
  int mt = swz / 6, nt = swz - mt * 6;      // nt minor: 6 consecutive share A panel (L2)
  int m0 = mt * 128, n0 = nt * 128;
  int tid = threadIdx.x;
  int lane = tid & 63, wid = tid >> 6;
  int wm = wid >> 1, wn = wid & 1;          // 2x2 waves, 64x64 each
  int lr = lane & 15, kg = lane >> 4;
  const char* Ag = (const char*)X + (size_t)m0 * 1024;
  const char* Bg = (const char*)W + (size_t)n0 * 1024;
  f32x4 acc[4][4] = {};
  for (int kt = 0; kt < 8; ++kt) {
    __syncthreads();
    stage_tile(Ag + kt * 128, 1024, As, tid);
    stage_tile(Bg + kt * 128, 1024, Bs, tid);
    __syncthreads();
    bf16x8 af[4], bfr[4];
#pragma unroll
    for (int i = 0; i < 4; ++i) af[i] = frag_from_f32(As, wm * 64 + i * 16 + lr, kg);
#pragma unroll
    for (int j = 0; j < 4; ++j) bfr[j] = frag_from_f32(Bs, wn * 64 + j * 16 + lr, kg);
#pragma unroll
    for (int i = 0; i < 4; ++i)
#pragma unroll
      for (int j = 0; j < 4; ++j)
        // swapped operands: lane holds C[m=lr][n = ... + kg*4 + r] (4 consecutive cols)
        acc[i][j] = __builtin_amdgcn_mfma_f32_16x16x32_bf16(bfr[j], af[i], acc[i][j], 0, 0, 0);
  }
#pragma unroll
  for (int i = 0; i < 4; ++i) {
    int row = m0 + wm * 64 + i * 16 + lr;
#pragma unroll
    for (int j = 0; j < 4; ++j) {
      int col = n0 + wn * 64 + j * 16 + kg * 4;
      uint2 pv;
      pv.x = (unsigned)f2bf(acc[i][j][0]) | ((unsigned)f2bf(acc[i][j][1]) << 16);
      pv.y = (unsigned)f2bf(acc[i][j][2]) | ((unsigned)f2bf(acc[i][j][3]) << 16);
      if (nt < 2) {
        *(uint2*)((char*)Q + ((size_t)row * 256 + col) * 2) = pv;
      } else {
        *(uint2*)((char*)KV + ((size_t)row * 512 + (col - 256)) * 2) = pv;
      }
    }
  }
}

// ---------------- dots: normalize k,v over d=32 and accumulate k^T v ----------------
// KV bf16 [65536][512] (k: cols 0..255, v: cols 256..511, 8 heads x 32 each)
// dots f32 [4][8][32][32] via atomicAdd (pre-zeroed).
__global__ __launch_bounds__(512) void dots_kernel(
    const __hip_bfloat16* __restrict__ KV, float* __restrict__ dots) {
  __shared__ float kh[2048];  // [head][tok8][32] f32
  __shared__ float vh[2048];
  int tid = threadIdx.x;
  int bid = blockIdx.x;
  int b = bid >> 6, chunk = bid & 63;           // 64 chunks of 256 tokens per batch
  size_t tok0 = (size_t)b * 16384 + (size_t)chunk * 256;
  int qd = tid >> 2, jj = tid & 3;              // quad per (token,head,k/v)
  int tko = qd >> 4;                            // 0..7 token within group
  int rem = qd & 15;
  int head = rem >> 1, kvs = rem & 1;
  int wid = tid >> 6;                           // wave = head for phase 2
  int lane = tid & 63;
  int dbase = (lane & 7) * 4, ebase = (lane >> 3) * 4;  // 8x8 lanes -> 4x4 outputs
  float acc[4][4] = {};
  const unsigned short* kvp = (const unsigned short*)KV;
  float* dst = (kvs ? vh : kh) + head * 256 + tko * 32 + jj * 8;
  for (int it = 0; it < 32; ++it) {
    // phase 1: load 8 tokens (full 1KB rows, coalesced), normalize into LDS
    size_t t = tok0 + (size_t)it * 8 + tko;
    ushort8 raw = *(const ushort8*)(kvp + t * 512 + (size_t)kvs * 256 + head * 32 + jj * 8);
    float x[8];
    float s = 0.f, ss = 0.f;
#pragma unroll
    for (int r = 0; r < 8; ++r) {
      x[r] = __uint_as_float((unsigned)raw[r] << 16);
      s += x[r]; ss += x[r] * x[r];
    }
    s += __shfl_xor(s, 1, 64);  s += __shfl_xor(s, 2, 64);
    ss += __shfl_xor(ss, 1, 64); ss += __shfl_xor(ss, 2, 64);
    float mean = s * (1.0f / 32.0f);
    float var = ss * (1.0f / 32.0f) - mean * mean;
    float rs = rsqrtf(var + 1e-5f);
    f32x4 y0 = {(x[0] - mean) * rs, (x[1] - mean) * rs, (x[2] - mean) * rs, (x[3] - mean) * rs};
    f32x4 y1 = {(x[4] - mean) * rs, (x[5] - mean) * rs, (x[6] - mean) * rs, (x[7] - mean) * rs};
    *(f32x4*)dst = y0;
    *(f32x4*)(dst + 4) = y1;
    __syncthreads();
    // phase 2: wave 'wid' accumulates its head's 32x32 outer products (4x4/thread)
#pragma unroll
    for (int tk = 0; tk < 8; ++tk) {
      f32x4 kk = *(const f32x4*)&kh[wid * 256 + tk * 32 + dbase];
      f32x4 vv = *(const f32x4*)&vh[wid * 256 + tk * 32 + ebase];
#pragma unroll
      for (int i = 0; i < 4; ++i)
#pragma unroll
        for (int j2 = 0; j2 < 4; ++j2)
          acc[i][j2] = fmaf(kk[i], vv[j2], acc[i][j2]);
    }
    __syncthreads();
  }
  float* dout = dots + (((size_t)b * 8 + wid) * 32) * 32;
#pragma unroll
  for (int i = 0; i < 4; ++i)
#pragma unroll
    for (int j2 = 0; j2 < 4; ++j2)
      atomicAdd(dout + (dbase + i) * 32 + ebase + j2, acc[i][j2]);
}

// ---------------- combine: W2T[b][o][e'] = sum_j dots[b,h,i,j] * w_out[o, h*32+j] / n ----------------
__global__ __launch_bounds__(256) void combine_kernel(
    const float* __restrict__ dots, const float* __restrict__ Wout,
    __hip_bfloat16* __restrict__ W2T) {
  int bid = blockIdx.x;
  int b = bid >> 8, o = bid & 255;
  int e = threadIdx.x;           // e' = h*32 + i
  int h = e >> 5;
  __shared__ float wrow[256];
  wrow[e] = Wout[o * 256 + e];
  __syncthreads();
  const float* dp = dots + (((size_t)b * 8 + h) * 32 + (e & 31)) * 32;
  const float* wp = wrow + h * 32;
  float s = 0.f;
#pragma unroll
  for (int j = 0; j < 32; ++j) s = fmaf(dp[j], wp[j], s);
  *((unsigned short*)W2T + ((size_t)b * 256 + o) * 256 + e) = f2bf(s * (1.0f / 16384.0f));
}

// ---------------- GEMM2: final[b] = q[b] @ W2T[b]^T + b_out ----------------
__global__ __launch_bounds__(256) void gemm_out(
    const __hip_bfloat16* __restrict__ Qm, const __hip_bfloat16* __restrict__ W2T,
    const float* __restrict__ bias, float* __restrict__ C) {
  __shared__ __align__(16) char As[16384];
  __shared__ __align__(16) char Bs[16384];
  int bid = blockIdx.x;
  int swz = (bid & 7) * 128 + (bid >> 3);   // 1024 = 8*128
  int mt = swz >> 1, nt = swz & 1;
  int m0 = mt * 128, n0 = nt * 128;
  int b = mt >> 7;                           // 128 M-tiles per batch
  int tid = threadIdx.x;
  int lane = tid & 63, wid = tid >> 6;
  int wm = wid >> 1, wn = wid & 1;
  int lr = lane & 15, kg = lane >> 4;
  const char* Ag = (const char*)Qm + (size_t)m0 * 512;
  const char* Bg = (const char*)W2T + (size_t)b * 131072 + (size_t)n0 * 512;
  f32x4 acc[4][4] = {};
  for (int kt = 0; kt < 4; ++kt) {          // BK = 64 bf16 = 128B rows
    __syncthreads();
    stage_tile(Ag + kt * 128, 512, As, tid);
    stage_tile(Bg + kt * 128, 512, Bs, tid);
    __syncthreads();
#pragma unroll
    for (int ks = 0; ks < 2; ++ks) {
      bf16x8 af[4], bfr[4];
#pragma unroll
      for (int i = 0; i < 4; ++i) af[i] = frag_from_bf16(As, wm * 64 + i * 16 + lr, kg, ks);
#pragma unroll
      for (int j = 0; j < 4; ++j) bfr[j] = frag_from_bf16(Bs, wn * 64 + j * 16 + lr, kg, ks);
#pragma unroll
      for (int i = 0; i < 4; ++i)
#pragma unroll
        for (int j = 0; j < 4; ++j)
          acc[i][j] = __builtin_amdgcn_mfma_f32_16x16x32_bf16(bfr[j], af[i], acc[i][j], 0, 0, 0);
    }
  }
#pragma unroll
  for (int i = 0; i < 4; ++i) {
    int row = m0 + wm * 64 + i * 16 + lr;
#pragma unroll
    for (int j = 0; j < 4; ++j) {
      int col = n0 + wn * 64 + j * 16 + kg * 4;
      f32x4 bo = *(const f32x4*)(bias + col);
      f32x4 v = acc[i][j] + bo;
      *(f32x4*)(C + (size_t)row * 256 + col) = v;
    }
  }
}

extern "C" void kernel_launch(void* const* d_in, const int* in_sizes, int n_in,
                              void* d_out, int out_size, void* d_ws, size_t ws_size,
                              hipStream_t stream) {
  const float* x     = (const float*)d_in[0];   // [4,16384,256]
  const float* w_qkv = (const float*)d_in[1];   // [768,256]
  const float* w_out = (const float*)d_in[2];   // [256,256]
  const float* b_out = (const float*)d_in[3];   // [256]
  float* out = (float*)d_out;

  char* ws = (char*)d_ws;
  __hip_bfloat16* Q    = (__hip_bfloat16*)ws;                         // 33,554,432 B
  float*          dots = (float*)(ws + 33554432);                     //    131,072 B
  __hip_bfloat16* W2T  = (__hip_bfloat16*)(ws + 33554432 + 131072);   //    524,288 B
  // k,v scratch lives in d_out (exactly 67.1MB); overwritten by gemm_out at the end.
  __hip_bfloat16* KV = (__hip_bfloat16*)d_out;

  hipMemsetAsync(dots, 0, 131072, stream);
  gemm_qkv<<<dim3(3072), dim3(256), 0, stream>>>(x, w_qkv, Q, KV);
  dots_kernel<<<dim3(256), dim3(512), 0, stream>>>(KV, dots);
  combine_kernel<<<dim3(1024), dim3(256), 0, stream>>>(dots, w_out, W2T);
  gemm_out<<<dim3(1024), dim3(256), 0, stream>>>(Q, W2T, b_out, out);
}

// Round 2
// 270.253 us; speedup vs baseline: 1.0650x; 1.0650x over previous
//
#include <hip/hip_runtime.h>
#include <hip/hip_bf16.h>

typedef float f32x4 __attribute__((ext_vector_type(4)));
typedef __bf16 bf16x8 __attribute__((ext_vector_type(8)));
typedef unsigned short ushort8 __attribute__((ext_vector_type(8)));

#define DEVINL __device__ __forceinline__

DEVINL void gload_lds16(const void* g, void* l) {
  __builtin_amdgcn_global_load_lds(
      (const __attribute__((address_space(1))) void*)g,
      (__attribute__((address_space(3))) void*)l, 16, 0, 0);
}

DEVINL unsigned short f2bf(float f) {
  unsigned int x = __float_as_uint(f);
  x += 0x7fffu + ((x >> 16) & 1u);
  return (unsigned short)(x >> 16);
}

// Stage a 128-row x 128-byte tile (f32 K=32 or bf16 K=64 rows).
// LDS[r][c] = global[r][c ^ (r&7)], linear LDS dest as gload_lds requires.
DEVINL void stage_tileA(const char* gbase, int ld_bytes, char* lds, int tid) {
#pragma unroll
  for (int p = 0; p < 4; ++p) {
    int r = p * 32 + (tid >> 3);
    int cs = (tid & 7) ^ (r & 7);
    gload_lds16(gbase + (size_t)r * ld_bytes + cs * 16, lds + p * 4096 + tid * 16);
  }
}

// Stage a 128-row x 64-byte bf16 tile (K=32). LDS[r][c] = global[r][c ^ ((r>>1)&3)].
DEVINL void stage_tileB(const char* gbase, int ld_bytes, char* lds, int tid) {
#pragma unroll
  for (int p = 0; p < 2; ++p) {
    int r = p * 64 + (tid >> 2);
    int cs = (tid & 3) ^ ((r >> 1) & 3);
    gload_lds16(gbase + (size_t)r * ld_bytes + cs * 16, lds + p * 4096 + tid * 16);
  }
}

DEVINL bf16x8 cvt8(f32x4 a, f32x4 b) {
  bf16x8 o;
  o[0] = (__bf16)a[0]; o[1] = (__bf16)a[1]; o[2] = (__bf16)a[2]; o[3] = (__bf16)a[3];
  o[4] = (__bf16)b[0]; o[5] = (__bf16)b[1]; o[6] = (__bf16)b[2]; o[7] = (__bf16)b[3];
  return o;
}

// fragment from f32 tile: row = 32 f32 = 128B, 8 chunks
DEVINL bf16x8 frag_from_f32(const char* lds, int r, int kg) {
  int c0 = (kg * 2) ^ (r & 7);
  int c1 = (kg * 2 + 1) ^ (r & 7);
  f32x4 f0 = *(const f32x4*)(lds + r * 128 + c0 * 16);
  f32x4 f1 = *(const f32x4*)(lds + r * 128 + c1 * 16);
  return cvt8(f0, f1);
}

// fragment from bf16 64B-row tile (K=32): chunk kg of 4
DEVINL bf16x8 fragB32(const char* lds, int r, int kg) {
  int c = kg ^ ((r >> 1) & 3);
  return *(const bf16x8*)(lds + r * 64 + c * 16);
}

// fragment from bf16 128B-row tile (K=64): ksub selects 32-wide K slice
DEVINL bf16x8 frag_from_bf16(const char* lds, int r, int kg, int ksub) {
  int c = (ksub * 4 + kg) ^ (r & 7);
  return *(const bf16x8*)(lds + r * 128 + c * 16);
}

// ---------------- prep: w_qkv f32 -> bf16 ----------------
__global__ __launch_bounds__(256) void prep_wb(const float* __restrict__ W,
                                               __hip_bfloat16* __restrict__ Wb) {
  int i = (blockIdx.x * 256 + threadIdx.x) * 4;
  f32x4 v = *(const f32x4*)(W + i);
  uint2 pv;
  pv.x = (unsigned)f2bf(v[0]) | ((unsigned)f2bf(v[1]) << 16);
  pv.y = (unsigned)f2bf(v[2]) | ((unsigned)f2bf(v[3]) << 16);
  *(uint2*)((unsigned short*)Wb + i) = pv;
}

// ---------------- GEMM1: qkv = x @ w_qkv^T (2-phase, dbuf) ----------------
__global__ __launch_bounds__(256) void gemm_qkv(
    const float* __restrict__ X, const __hip_bfloat16* __restrict__ Wb,
    __hip_bfloat16* __restrict__ Q, __hip_bfloat16* __restrict__ KV) {
  __shared__ __align__(16) char As[2][16384];
  __shared__ __align__(16) char Bs[2][8192];
  int bid = blockIdx.x;
  int swz = (bid & 7) * 384 + (bid >> 3);   // 3072 = 8*384, bijective XCD swizzle
  int mt = swz / 6, nt = swz - mt * 6;      // nt minor: 6 consecutive share A panel
  int m0 = mt * 128, n0 = nt * 128;
  int tid = threadIdx.x;
  int lane = tid & 63, wid = tid >> 6;
  int wm = wid >> 1, wn = wid & 1;
  int lr = lane & 15, kg = lane >> 4;
  const char* Ag = (const char*)X + (size_t)m0 * 1024;
  const char* Bg = (const char*)Wb + (size_t)n0 * 512;
  f32x4 acc[4][4] = {};
  stage_tileA(Ag, 1024, As[0], tid);
  stage_tileB(Bg, 512, Bs[0], tid);
  __syncthreads();
  for (int kt = 0; kt < 8; ++kt) {
    int cur = kt & 1;
    if (kt < 7) {  // prefetch next K-tile into the other buffer
      stage_tileA(Ag + (kt + 1) * 128, 1024, As[cur ^ 1], tid);
      stage_tileB(Bg + (kt + 1) * 64, 512, Bs[cur ^ 1], tid);
    }
    bf16x8 af[4], bfr[4];
#pragma unroll
    for (int i = 0; i < 4; ++i) af[i] = frag_from_f32(As[cur], wm * 64 + i * 16 + lr, kg);
#pragma unroll
    for (int j = 0; j < 4; ++j) bfr[j] = fragB32(Bs[cur], wn * 64 + j * 16 + lr, kg);
#pragma unroll
    for (int i = 0; i < 4; ++i)
#pragma unroll
      for (int j = 0; j < 4; ++j)
        acc[i][j] = __builtin_amdgcn_mfma_f32_16x16x32_bf16(bfr[j], af[i], acc[i][j], 0, 0, 0);
    __syncthreads();  // single barrier/step: drains prefetch (vmcnt) for next iter
  }
#pragma unroll
  for (int i = 0; i < 4; ++i) {
    int row = m0 + wm * 64 + i * 16 + lr;
#pragma unroll
    for (int j = 0; j < 4; ++j) {
      int col = n0 + wn * 64 + j * 16 + kg * 4;
      uint2 pv;
      pv.x = (unsigned)f2bf(acc[i][j][0]) | ((unsigned)f2bf(acc[i][j][1]) << 16);
      pv.y = (unsigned)f2bf(acc[i][j][2]) | ((unsigned)f2bf(acc[i][j][3]) << 16);
      if (nt < 2) {
        *(uint2*)((char*)Q + ((size_t)row * 256 + col) * 2) = pv;
      } else {
        *(uint2*)((char*)KV + ((size_t)row * 512 + (col - 256)) * 2) = pv;
      }
    }
  }
}

// ---------------- dots: per-wave-per-head, no block barriers ----------------
// KV bf16 [65536][512]; partial f32 [8 copies][4][8][32][32] via atomicAdd.
__global__ __launch_bounds__(512) void dots_kernel(
    const __hip_bfloat16* __restrict__ KV, float* __restrict__ partial) {
  __shared__ float buf[8][2][8][32];  // [wave=head][k/v][tok][dim] 16KB
  int tid = threadIdx.x, bid = blockIdx.x;
  int b = bid >> 7, chunk = bid & 127;           // 128 chunks x 128 tokens per batch
  size_t tok0 = (size_t)b * 16384 + (size_t)chunk * 128;
  int w = tid >> 6, lane = tid & 63;             // wave w handles head w
  int t = lane >> 3;                             // token 0..7 within group
  int kvs = (lane >> 2) & 1;                     // k or v
  int q = lane & 3;                              // 8-elem quad within dim-32 row
  const unsigned short* kvp = (const unsigned short*)KV;
  int dbase = (lane & 7) * 4, ebase = (lane >> 3) * 4;
  float acc[4][4] = {};
  float* dst = &buf[w][kvs][t][q * 8];
  size_t off0 = (size_t)kvs * 256 + w * 32 + q * 8;
  ushort8 raw = *(const ushort8*)(kvp + (tok0 + t) * 512 + off0);
  for (int it = 0; it < 16; ++it) {
    ushort8 curv = raw;
    if (it < 15)  // register prefetch of next 8-token group
      raw = *(const ushort8*)(kvp + (tok0 + (size_t)(it + 1) * 8 + t) * 512 + off0);
    float x[8];
    float s = 0.f, ss = 0.f;
#pragma unroll
    for (int r = 0; r < 8; ++r) {
      x[r] = __uint_as_float((unsigned)curv[r] << 16);
      s += x[r]; ss += x[r] * x[r];
    }
    s += __shfl_xor(s, 1, 64);  s += __shfl_xor(s, 2, 64);
    ss += __shfl_xor(ss, 1, 64); ss += __shfl_xor(ss, 2, 64);
    float mean = s * (1.0f / 32.0f);
    float var = ss * (1.0f / 32.0f) - mean * mean;
    float rs = rsqrtf(var + 1e-5f);
    f32x4 y0 = {(x[0] - mean) * rs, (x[1] - mean) * rs, (x[2] - mean) * rs, (x[3] - mean) * rs};
    f32x4 y1 = {(x[4] - mean) * rs, (x[5] - mean) * rs, (x[6] - mean) * rs, (x[7] - mean) * rs};
    *(f32x4*)dst = y0;
    *(f32x4*)(dst + 4) = y1;
    // wave-private LDS slice: only lgkmcnt ordering needed (compiler-inserted)
#pragma unroll
    for (int tk = 0; tk < 8; ++tk) {
      f32x4 kk = *(const f32x4*)&buf[w][0][tk][dbase];
      f32x4 vv = *(const f32x4*)&buf[w][1][tk][ebase];
#pragma unroll
      for (int i = 0; i < 4; ++i)
#pragma unroll
        for (int j2 = 0; j2 < 4; ++j2)
          acc[i][j2] = fmaf(kk[i], vv[j2], acc[i][j2]);
    }
  }
  float* dout = partial + ((size_t)(bid & 7) * 32 + (size_t)b * 8 + w) * 1024;
#pragma unroll
  for (int i = 0; i < 4; ++i)
#pragma unroll
    for (int j2 = 0; j2 < 4; ++j2)
      atomicAdd(dout + (dbase + i) * 32 + ebase + j2, acc[i][j2]);
}

// ---------------- reduce 8 partial copies -> dots ----------------
__global__ __launch_bounds__(256) void reduce_partials(
    const float* __restrict__ partial, float* __restrict__ dots) {
  int i = blockIdx.x * 256 + threadIdx.x;  // 32768 total
  float s = 0.f;
#pragma unroll
  for (int c = 0; c < 8; ++c) s += partial[c * 32768 + i];
  dots[i] = s;
}

// ---------------- combine: W2T[b][o][e'] = sum_j dots[b,h,i,j]*w_out[o,h*32+j]/n ----------------
__global__ __launch_bounds__(256) void combine_kernel(
    const float* __restrict__ dots, const float* __restrict__ Wout,
    __hip_bfloat16* __restrict__ W2T) {
  int bid = blockIdx.x;
  int b = bid >> 8, o = bid & 255;
  int e = threadIdx.x;           // e' = h*32 + i
  int h = e >> 5;
  __shared__ float wrow[256];
  wrow[e] = Wout[o * 256 + e];
  __syncthreads();
  const float* dp = dots + (((size_t)b * 8 + h) * 32 + (e & 31)) * 32;
  const float* wp = wrow + h * 32;
  float s = 0.f;
#pragma unroll
  for (int j = 0; j < 32; ++j) s = fmaf(dp[j], wp[j], s);
  *((unsigned short*)W2T + ((size_t)b * 256 + o) * 256 + e) = f2bf(s * (1.0f / 16384.0f));
}

// ---------------- GEMM2: final[b] = q[b] @ W2T[b]^T + b_out (2-phase, dbuf) ----------------
__global__ __launch_bounds__(256) void gemm_out(
    const __hip_bfloat16* __restrict__ Qm, const __hip_bfloat16* __restrict__ W2T,
    const float* __restrict__ bias, float* __restrict__ C) {
  __shared__ __align__(16) char As[2][16384];
  __shared__ __align__(16) char Bs[2][16384];
  int bid = blockIdx.x;
  int swz = (bid & 7) * 128 + (bid >> 3);   // 1024 = 8*128
  int mt = swz >> 1, nt = swz & 1;
  int m0 = mt * 128, n0 = nt * 128;
  int b = mt >> 7;                           // 128 M-tiles per batch
  int tid = threadIdx.x;
  int lane = tid & 63, wid = tid >> 6;
  int wm = wid >> 1, wn = wid & 1;
  int lr = lane & 15, kg = lane >> 4;
  const char* Ag = (const char*)Qm + (size_t)m0 * 512;
  const char* Bg = (const char*)W2T + (size_t)b * 131072 + (size_t)n0 * 512;
  f32x4 acc[4][4] = {};
  stage_tileA(Ag, 512, As[0], tid);
  stage_tileA(Bg, 512, Bs[0], tid);
  __syncthreads();
  for (int kt = 0; kt < 4; ++kt) {          // BK = 64 bf16 = 128B rows
    int cur = kt & 1;
    if (kt < 3) {
      stage_tileA(Ag + (kt + 1) * 128, 512, As[cur ^ 1], tid);
      stage_tileA(Bg + (kt + 1) * 128, 512, Bs[cur ^ 1], tid);
    }
#pragma unroll
    for (int ks = 0; ks < 2; ++ks) {
      bf16x8 af[4], bfr[4];
#pragma unroll
      for (int i = 0; i < 4; ++i) af[i] = frag_from_bf16(As[cur], wm * 64 + i * 16 + lr, kg, ks);
#pragma unroll
      for (int j = 0; j < 4; ++j) bfr[j] = frag_from_bf16(Bs[cur], wn * 64 + j * 16 + lr, kg, ks);
#pragma unroll
      for (int i = 0; i < 4; ++i)
#pragma unroll
        for (int j = 0; j < 4; ++j)
          acc[i][j] = __builtin_amdgcn_mfma_f32_16x16x32_bf16(bfr[j], af[i], acc[i][j], 0, 0, 0);
    }
    __syncthreads();
  }
#pragma unroll
  for (int i = 0; i < 4; ++i) {
    int row = m0 + wm * 64 + i * 16 + lr;
#pragma unroll
    for (int j = 0; j < 4; ++j) {
      int col = n0 + wn * 64 + j * 16 + kg * 4;
      f32x4 bo = *(const f32x4*)(bias + col);
      f32x4 v = acc[i][j] + bo;
      *(f32x4*)(C + (size_t)row * 256 + col) = v;
    }
  }
}

extern "C" void kernel_launch(void* const* d_in, const int* in_sizes, int n_in,
                              void* d_out, int out_size, void* d_ws, size_t ws_size,
                              hipStream_t stream) {
  const float* x     = (const float*)d_in[0];   // [4,16384,256]
  const float* w_qkv = (const float*)d_in[1];   // [768,256]
  const float* w_out = (const float*)d_in[2];   // [256,256]
  const float* b_out = (const float*)d_in[3];   // [256]
  float* out = (float*)d_out;

  char* ws = (char*)d_ws;
  __hip_bfloat16* Q    = (__hip_bfloat16*)ws;                     // 33,554,432 B
  float* partial       = (float*)(ws + 33554432);                 //  1,048,576 B
  float* dots          = (float*)(ws + 34603008);                 //    131,072 B
  __hip_bfloat16* W2T  = (__hip_bfloat16*)(ws + 34734080);        //    524,288 B
  __hip_bfloat16* Wb   = (__hip_bfloat16*)(ws + 35258368);        //    393,216 B
  // k,v scratch lives in d_out (67.1MB); overwritten by gemm_out at the end.
  __hip_bfloat16* KV = (__hip_bfloat16*)d_out;

  hipMemsetAsync(partial, 0, 1048576, stream);
  prep_wb<<<dim3(192), dim3(256), 0, stream>>>(w_qkv, Wb);
  gemm_qkv<<<dim3(3072), dim3(256), 0, stream>>>(x, Wb, Q, KV);
  dots_kernel<<<dim3(512), dim3(512), 0, stream>>>(KV, partial);
  reduce_partials<<<dim3(128), dim3(256), 0, stream>>>(partial, dots);
  combine_kernel<<<dim3(1024), dim3(256), 0, stream>>>(dots, w_out, W2T);
  gemm_out<<<dim3(1024), dim3(256), 0, stream>>>(Q, W2T, b_out, out);
}